// Round 2
// baseline (666.478 us; speedup 1.0000x reference)
//
#include <hip/hip_runtime.h>
#include <stdint.h>

// Problem constants
#define Bz  4
#define Sz  2048
#define Hz  1024
#define NHz 8
#define HDz 128
#define Mz  (Bz*Sz)          // 8192 rows for all GEMMs

typedef __attribute__((ext_vector_type(8))) short bf16x8;   // 8 bf16 = 4 VGPRs
typedef __attribute__((ext_vector_type(4))) float f32x4;

__device__ __forceinline__ unsigned short f2bf(float x) {
  union { float f; unsigned int u; } c; c.f = x;
  unsigned int u = c.u;
  return (unsigned short)((u + 0x7FFFu + ((u >> 16) & 1u)) >> 16);  // RNE
}

__device__ __forceinline__ void gl2lds16(const unsigned short* g, unsigned short* l) {
  __builtin_amdgcn_global_load_lds(
      (const __attribute__((address_space(1))) unsigned int*)g,
      (__attribute__((address_space(3))) unsigned int*)l, 16, 0, 0);
}

// ---------------------------------------------------------------- cvt f32->bf16
__global__ __launch_bounds__(256)
void cvt_kernel(const float* __restrict__ in, unsigned short* __restrict__ out, int n) {
  const int n4 = n >> 2;
  for (int i = blockIdx.x * blockDim.x + threadIdx.x; i < n4; i += gridDim.x * blockDim.x) {
    float4 v = ((const float4*)in)[i];
    ushort4 o;
    o.x = f2bf(v.x); o.y = f2bf(v.y); o.z = f2bf(v.z); o.w = f2bf(v.w);
    ((ushort4*)out)[i] = o;
  }
}

// one launch for all 4 weight matrices (each Hz*Hz elements)
__global__ __launch_bounds__(256)
void cvt4_kernel(const float* __restrict__ w0, const float* __restrict__ w1,
                 const float* __restrict__ w2, const float* __restrict__ w3,
                 unsigned short* __restrict__ o0, unsigned short* __restrict__ o1,
                 unsigned short* __restrict__ o2, unsigned short* __restrict__ o3) {
  const int which = blockIdx.y;
  const float* in = (which == 0) ? w0 : (which == 1) ? w1 : (which == 2) ? w2 : w3;
  unsigned short* out = (which == 0) ? o0 : (which == 1) ? o1 : (which == 2) ? o2 : o3;
  const int n4 = (Hz * Hz) >> 2;
  for (int i = blockIdx.x * blockDim.x + threadIdx.x; i < n4; i += gridDim.x * blockDim.x) {
    float4 v = ((const float4*)in)[i];
    ushort4 o;
    o.x = f2bf(v.x); o.y = f2bf(v.y); o.z = f2bf(v.z); o.w = f2bf(v.w);
    ((ushort4*)out)[i] = o;
  }
}

// ---------------------------------------------------------------- GEMM  C = A * B^T
// A: [8192][1024] bf16 row-major; Bw: [1024][1024] bf16 row-major ([out,in] weight)
// BF16_OUT: write bf16 row-major [8192][1024]        (alpha applied)
// VT_OUT:   write bf16 transposed-per-head [B*NH*HD][S] (for V)
template<bool BF16_OUT, bool VT_OUT>
__global__ __launch_bounds__(256)
void gemm_bt_k(const unsigned short* __restrict__ A,
               const unsigned short* __restrict__ Bw,
               void* __restrict__ Cv, float alpha)
{
  __shared__ __align__(16) unsigned short Asm[128 * 64];
  __shared__ __align__(16) unsigned short Bsm[128 * 64];
  const int tid = threadIdx.x;
  const int w  = tid >> 6, l = tid & 63;
  const int lc = l & 15,  lg = l >> 4;
  const int wr = w >> 1,  wc = w & 1;
  const int bm = blockIdx.x * 128;
  const int bn = blockIdx.y * 128;

  f32x4 acc[4][4];
#pragma unroll
  for (int i = 0; i < 4; i++)
#pragma unroll
    for (int j = 0; j < 4; j++) acc[i][j] = (f32x4){0.f, 0.f, 0.f, 0.f};

  const int srow = w * 32 + (l >> 3);   // staging row (+ i*8)
  const int scol = (l & 7) * 8;         // staging col in elements

  for (int kt = 0; kt < 16; kt++) {
    const int k0 = kt * 64;
    __syncthreads();
#pragma unroll
    for (int i = 0; i < 4; i++) {
      gl2lds16(A  + (size_t)(bm + srow + i * 8) * Hz + k0 + scol, &Asm[(w * 32 + i * 8) * 64]);
      gl2lds16(Bw + (size_t)(bn + srow + i * 8) * Hz + k0 + scol, &Bsm[(w * 32 + i * 8) * 64]);
    }
    __syncthreads();

#pragma unroll
    for (int kk = 0; kk < 2; kk++) {
      bf16x8 af[4], bf[4];
#pragma unroll
      for (int t = 0; t < 4; t++) {
        af[t] = *(const bf16x8*)&Asm[(wr * 64 + t * 16 + lc) * 64 + kk * 32 + lg * 8];
        bf[t] = *(const bf16x8*)&Bsm[(wc * 64 + t * 16 + lc) * 64 + kk * 32 + lg * 8];
      }
#pragma unroll
      for (int mt = 0; mt < 4; mt++)
#pragma unroll
        for (int nt = 0; nt < 4; nt++)
          acc[mt][nt] = __builtin_amdgcn_mfma_f32_16x16x32_bf16(af[mt], bf[nt], acc[mt][nt], 0, 0, 0);
    }
  }

#pragma unroll
  for (int mt = 0; mt < 4; mt++) {
#pragma unroll
    for (int nt = 0; nt < 4; nt++) {
      const int row0 = bm + wr * 64 + mt * 16 + lg * 4;
      const int col  = bn + wc * 64 + nt * 16 + lc;
      if (VT_OUT) {
        // V^T layout: [(b*NH+nh)*HD + hd][S];  n = nh*128+hd, m = b*2048+s
        unsigned short* Vt = (unsigned short*)Cv;
        ushort4 pk;
        pk.x = f2bf(acc[mt][nt][0] * alpha);
        pk.y = f2bf(acc[mt][nt][1] * alpha);
        pk.z = f2bf(acc[mt][nt][2] * alpha);
        pk.w = f2bf(acc[mt][nt][3] * alpha);
        const size_t idx = ((size_t)((row0 >> 11) << 10) + col) * Sz + (row0 & 2047);
        *(ushort4*)&Vt[idx] = pk;
      } else if (BF16_OUT) {
        unsigned short* C = (unsigned short*)Cv;
#pragma unroll
        for (int r = 0; r < 4; r++)
          C[(size_t)(row0 + r) * Hz + col] = f2bf(acc[mt][nt][r] * alpha);
      } else {
        float* C = (float*)Cv;
#pragma unroll
        for (int r = 0; r < 4; r++)
          C[(size_t)(row0 + r) * Hz + col] = acc[mt][nt][r] * alpha;
      }
    }
  }
}

// ---------------------------------------------------------------- flash attention
// Q,K: [B,S,H] bf16 (Q pre-scaled by log2(e)/sqrt(128) -> exp2-space softmax);
// Vt: [B*NH*HD][S] bf16;  O: [B,S,H] bf16
__global__ __launch_bounds__(256)
void attn_fwd(const unsigned short* __restrict__ Q,
              const unsigned short* __restrict__ K,
              const unsigned short* __restrict__ Vt,
              unsigned short* __restrict__ O)
{
  const int qblk = blockIdx.x;            // 0..31  (S/64)
  const int bh   = blockIdx.y;            // 0..31  (B*NH)
  const int b = bh >> 3, nh = bh & 7;
  const int w = threadIdx.x >> 6, l = threadIdx.x & 63;
  const int lc = l & 15, lg = l >> 4;

  __shared__ __align__(16) unsigned short Plds[4][16][72];  // per-wave, padded

  const unsigned short* Qbase = Q + ((size_t)b * Sz + qblk * 64 + w * 16) * Hz + nh * HDz;
  bf16x8 qf[4];
#pragma unroll
  for (int ks = 0; ks < 4; ks++)
    qf[ks] = *(const bf16x8*)(Qbase + (size_t)lc * Hz + ks * 32 + lg * 8);

  const unsigned short* Kbase = K  + (size_t)b * Sz * Hz + nh * HDz;
  const unsigned short* Vbase = Vt + (size_t)bh * HDz * Sz;

  f32x4 acc[8];
#pragma unroll
  for (int i = 0; i < 8; i++) acc[i] = (f32x4){0.f, 0.f, 0.f, 0.f};
  float mrow[4] = {-1e30f, -1e30f, -1e30f, -1e30f};
  float lrow[4] = {0.f, 0.f, 0.f, 0.f};

  for (int kt = 0; kt < Sz / 64; kt++) {
    // ---- scores (exp2-space): S_tile[16 q][64 k] per wave
    f32x4 s[4];
#pragma unroll
    for (int nt = 0; nt < 4; nt++) s[nt] = (f32x4){0.f, 0.f, 0.f, 0.f};
#pragma unroll
    for (int ks = 0; ks < 4; ks++) {
#pragma unroll
      for (int nt = 0; nt < 4; nt++) {
        bf16x8 kf = *(const bf16x8*)(Kbase + (size_t)(kt * 64 + nt * 16 + lc) * Hz + ks * 32 + lg * 8);
        s[nt] = __builtin_amdgcn_mfma_f32_16x16x32_bf16(qf[ks], kf, s[nt], 0, 0, 0);
      }
    }

    // ---- online softmax, exp2-space, defer-max (THR=8 -> P <= 256, f32-safe)
#pragma unroll
    for (int r = 0; r < 4; r++) {
      float tm = fmaxf(fmaxf(s[0][r], s[1][r]), fmaxf(s[2][r], s[3][r]));
      tm = fmaxf(tm, __shfl_xor(tm, 1));
      tm = fmaxf(tm, __shfl_xor(tm, 2));
      tm = fmaxf(tm, __shfl_xor(tm, 4));
      tm = fmaxf(tm, __shfl_xor(tm, 8));
      if (tm > mrow[r] + 8.0f) {          // rescale only on significant max growth
        const float sc = exp2f(mrow[r] - tm);
        mrow[r] = tm;
        lrow[r] *= sc;
#pragma unroll
        for (int nt = 0; nt < 8; nt++) acc[nt][r] *= sc;
      }
      float rs = 0.f;
#pragma unroll
      for (int nt = 0; nt < 4; nt++) {
        float p = exp2f(s[nt][r] - mrow[r]);
        s[nt][r] = p;
        rs += p;
      }
      rs += __shfl_xor(rs, 1);
      rs += __shfl_xor(rs, 2);
      rs += __shfl_xor(rs, 4);
      rs += __shfl_xor(rs, 8);
      lrow[r] += rs;
    }

    // ---- P (f32, D-layout) -> bf16 -> LDS (per-wave region, no cross-wave sync)
#pragma unroll
    for (int nt = 0; nt < 4; nt++)
#pragma unroll
      for (int r = 0; r < 4; r++)
        Plds[w][lg * 4 + r][nt * 16 + lc] = f2bf(s[nt][r]);

    // ---- PV: acc[16 q][128 d] += P[16 q][64 k] * V[64 k][128 d]
#pragma unroll
    for (int kk = 0; kk < 2; kk++) {
      bf16x8 pf = *(const bf16x8*)&Plds[w][lc][kk * 32 + lg * 8];
#pragma unroll
      for (int nt = 0; nt < 8; nt++) {
        bf16x8 vf = *(const bf16x8*)(Vbase + (size_t)(nt * 16 + lc) * Sz + kt * 64 + kk * 32 + lg * 8);
        acc[nt] = __builtin_amdgcn_mfma_f32_16x16x32_bf16(pf, vf, acc[nt], 0, 0, 0);
      }
    }
  }

  // ---- epilogue: normalize and store O[B,S,H] bf16
#pragma unroll
  for (int nt = 0; nt < 8; nt++)
#pragma unroll
    for (int r = 0; r < 4; r++) {
      const size_t row = (size_t)b * Sz + qblk * 64 + w * 16 + lg * 4 + r;
      O[row * Hz + nh * HDz + nt * 16 + lc] = f2bf(acc[nt][r] / lrow[r]);
    }
}

// ---------------------------------------------------------------- launch
extern "C" void kernel_launch(void* const* d_in, const int* in_sizes, int n_in,
                              void* d_out, int out_size, void* d_ws, size_t ws_size,
                              hipStream_t stream) {
  const float* hs = (const float*)d_in[0];
  const float* Wq = (const float*)d_in[1];
  const float* Wk = (const float*)d_in[2];
  const float* Wv = (const float*)d_in[3];
  const float* Wo = (const float*)d_in[4];

  const size_t NEL = (size_t)Mz * Hz;   // 8388608
  const size_t WEL = (size_t)Hz * Hz;   // 1048576

  unsigned short* p = (unsigned short*)d_ws;
  unsigned short* hs_bf = p; p += NEL;
  unsigned short* Wq_bf = p; p += WEL;
  unsigned short* Wk_bf = p; p += WEL;
  unsigned short* Wv_bf = p; p += WEL;
  unsigned short* Wo_bf = p; p += WEL;
  unsigned short* Qb    = p; p += NEL;
  unsigned short* Kb    = p; p += NEL;
  unsigned short* Vtb   = p; p += NEL;
  unsigned short* Ob    = hs_bf;        // alias: hs_bf dead after V GEMM
  // total ws use: ~75.5 MB

  cvt_kernel<<<2048, 256, 0, stream>>>(hs, hs_bf, (int)NEL);
  cvt4_kernel<<<dim3(512, 4), 256, 0, stream>>>(Wq, Wk, Wv, Wo,
                                                Wq_bf, Wk_bf, Wv_bf, Wo_bf);

  dim3 gg(Mz / 128, Hz / 128);  // 64 x 8
  const float qscale = 0.08838834764831845f * 1.44269504088896340736f; // 1/sqrt(128) * log2(e)
  gemm_bt_k<true,  false><<<gg, 256, 0, stream>>>(hs_bf, Wq_bf, Qb,  qscale);
  gemm_bt_k<true,  false><<<gg, 256, 0, stream>>>(hs_bf, Wk_bf, Kb,  1.0f);
  gemm_bt_k<true,  true ><<<gg, 256, 0, stream>>>(hs_bf, Wv_bf, Vtb, 1.0f);

  attn_fwd<<<dim3(Sz / 64, Bz * NHz), 256, 0, stream>>>(Qb, Kb, Vtb, Ob);

  gemm_bt_k<false, false><<<gg, 256, 0, stream>>>(Ob, Wo_bf, (float*)d_out, 1.0f);
}

// Round 3
// 350.281 us; speedup vs baseline: 1.9027x; 1.9027x over previous
//
#include <hip/hip_runtime.h>
#include <stdint.h>

// Problem constants
#define Bz  4
#define Sz  2048
#define Hz  1024
#define NHz 8
#define HDz 128
#define Mz  (Bz*Sz)          // 8192 rows for all GEMMs

typedef __attribute__((ext_vector_type(8))) short bf16x8;   // 8 bf16 = 4 VGPRs
typedef __attribute__((ext_vector_type(4))) float f32x4;

__device__ __forceinline__ unsigned short f2bf(float x) {
  union { float f; unsigned int u; } c; c.f = x;
  unsigned int u = c.u;
  return (unsigned short)((u + 0x7FFFu + ((u >> 16) & 1u)) >> 16);  // RNE
}

__device__ __forceinline__ void gl2lds16(const unsigned short* g, unsigned short* l) {
  __builtin_amdgcn_global_load_lds(
      (const __attribute__((address_space(1))) unsigned int*)g,
      (__attribute__((address_space(3))) unsigned int*)l, 16, 0, 0);
}

// ---------------------------------------------------------------- cvt f32->bf16
__global__ __launch_bounds__(256)
void cvt_kernel(const float* __restrict__ in, unsigned short* __restrict__ out, int n) {
  const int n4 = n >> 2;
  for (int i = blockIdx.x * blockDim.x + threadIdx.x; i < n4; i += gridDim.x * blockDim.x) {
    float4 v = ((const float4*)in)[i];
    ushort4 o;
    o.x = f2bf(v.x); o.y = f2bf(v.y); o.z = f2bf(v.z); o.w = f2bf(v.w);
    ((ushort4*)out)[i] = o;
  }
}

// one launch for all 4 weight matrices (each Hz*Hz elements)
__global__ __launch_bounds__(256)
void cvt4_kernel(const float* __restrict__ w0, const float* __restrict__ w1,
                 const float* __restrict__ w2, const float* __restrict__ w3,
                 unsigned short* __restrict__ o0, unsigned short* __restrict__ o1,
                 unsigned short* __restrict__ o2, unsigned short* __restrict__ o3) {
  const int which = blockIdx.y;
  const float* in = (which == 0) ? w0 : (which == 1) ? w1 : (which == 2) ? w2 : w3;
  unsigned short* out = (which == 0) ? o0 : (which == 1) ? o1 : (which == 2) ? o2 : o3;
  const int n4 = (Hz * Hz) >> 2;
  for (int i = blockIdx.x * blockDim.x + threadIdx.x; i < n4; i += gridDim.x * blockDim.x) {
    float4 v = ((const float4*)in)[i];
    ushort4 o;
    o.x = f2bf(v.x); o.y = f2bf(v.y); o.z = f2bf(v.z); o.w = f2bf(v.w);
    ((ushort4*)out)[i] = o;
  }
}

// ---------------------------------------------------------------- GEMM  C = A * B^T
template<bool BF16_OUT, bool VT_OUT>
__global__ __launch_bounds__(256)
void gemm_bt_k(const unsigned short* __restrict__ A,
               const unsigned short* __restrict__ Bw,
               void* __restrict__ Cv, float alpha)
{
  __shared__ __align__(16) unsigned short Asm[128 * 64];
  __shared__ __align__(16) unsigned short Bsm[128 * 64];
  const int tid = threadIdx.x;
  const int w  = tid >> 6, l = tid & 63;
  const int lc = l & 15,  lg = l >> 4;
  const int wr = w >> 1,  wc = w & 1;
  const int bm = blockIdx.x * 128;
  const int bn = blockIdx.y * 128;

  f32x4 acc[4][4];
#pragma unroll
  for (int i = 0; i < 4; i++)
#pragma unroll
    for (int j = 0; j < 4; j++) acc[i][j] = (f32x4){0.f, 0.f, 0.f, 0.f};

  const int srow = w * 32 + (l >> 3);   // staging row (+ i*8)
  const int scol = (l & 7) * 8;         // staging col in elements

  for (int kt = 0; kt < 16; kt++) {
    const int k0 = kt * 64;
    __syncthreads();
#pragma unroll
    for (int i = 0; i < 4; i++) {
      gl2lds16(A  + (size_t)(bm + srow + i * 8) * Hz + k0 + scol, &Asm[(w * 32 + i * 8) * 64]);
      gl2lds16(Bw + (size_t)(bn + srow + i * 8) * Hz + k0 + scol, &Bsm[(w * 32 + i * 8) * 64]);
    }
    __syncthreads();

#pragma unroll
    for (int kk = 0; kk < 2; kk++) {
      bf16x8 af[4], bf[4];
#pragma unroll
      for (int t = 0; t < 4; t++) {
        af[t] = *(const bf16x8*)&Asm[(wr * 64 + t * 16 + lc) * 64 + kk * 32 + lg * 8];
        bf[t] = *(const bf16x8*)&Bsm[(wc * 64 + t * 16 + lc) * 64 + kk * 32 + lg * 8];
      }
#pragma unroll
      for (int mt = 0; mt < 4; mt++)
#pragma unroll
        for (int nt = 0; nt < 4; nt++)
          acc[mt][nt] = __builtin_amdgcn_mfma_f32_16x16x32_bf16(af[mt], bf[nt], acc[mt][nt], 0, 0, 0);
    }
  }

#pragma unroll
  for (int mt = 0; mt < 4; mt++) {
#pragma unroll
    for (int nt = 0; nt < 4; nt++) {
      const int row0 = bm + wr * 64 + mt * 16 + lg * 4;
      const int col  = bn + wc * 64 + nt * 16 + lc;
      if (VT_OUT) {
        unsigned short* Vt = (unsigned short*)Cv;
        ushort4 pk;
        pk.x = f2bf(acc[mt][nt][0] * alpha);
        pk.y = f2bf(acc[mt][nt][1] * alpha);
        pk.z = f2bf(acc[mt][nt][2] * alpha);
        pk.w = f2bf(acc[mt][nt][3] * alpha);
        const size_t idx = ((size_t)((row0 >> 11) << 10) + col) * Sz + (row0 & 2047);
        *(ushort4*)&Vt[idx] = pk;
      } else if (BF16_OUT) {
        unsigned short* C = (unsigned short*)Cv;
#pragma unroll
        for (int r = 0; r < 4; r++)
          C[(size_t)(row0 + r) * Hz + col] = f2bf(acc[mt][nt][r] * alpha);
      } else {
        float* C = (float*)Cv;
#pragma unroll
        for (int r = 0; r < 4; r++)
          C[(size_t)(row0 + r) * Hz + col] = acc[mt][nt][r] * alpha;
      }
    }
  }
}

// ---------------------------------------------------------------- flash attention
// Q,K: [B,S,H] bf16 (Q pre-scaled by log2(e)/sqrt(128) -> exp2-space softmax);
// Vt: [B*NH*HD][S] bf16;  O: [B,S,H] bf16
// Block: 256 thr (4 waves), 128 q-rows/block (32/wave). K dbuf LDS, V single, P per-wave.
__global__ __launch_bounds__(256, 2)
void attn_fwd(const unsigned short* __restrict__ Q,
              const unsigned short* __restrict__ K,
              const unsigned short* __restrict__ Vt,
              unsigned short* __restrict__ O)
{
  // bijective XCD swizzle: 512 blocks -> each XCD gets 64 consecutive wg ids
  // (4 heads/XCD -> K+V working set 4MB, fits per-XCD L2)
  const int bid = blockIdx.x;
  const int wg  = (bid & 7) * 64 + (bid >> 3);
  const int qb  = wg & 15;               // q-block: rows qb*128..+127
  const int bh  = wg >> 4;               // 0..31
  const int b = bh >> 3, nh = bh & 7;
  const int w = threadIdx.x >> 6, l = threadIdx.x & 63;
  const int lc = l & 15, lg = l >> 4;

  __shared__ __align__(16) unsigned short Ksm[2][64 * 128]; // 32 KB, dbuf
  __shared__ __align__(16) unsigned short Vsm[128 * 64];    // 16 KB
  __shared__ __align__(16) unsigned short Psm[4][16 * 64];  //  8 KB (per-wave, reused per m)

  // ---- Q fragments (rows w*32 + mt*16 + lc)
  bf16x8 qf[2][4];
#pragma unroll
  for (int mt = 0; mt < 2; mt++)
#pragma unroll
    for (int ks = 0; ks < 4; ks++)
      qf[mt][ks] = *(const bf16x8*)(Q + ((size_t)b * Sz + qb * 128 + w * 32 + mt * 16 + lc) * Hz
                                      + nh * HDz + ks * 32 + lg * 8);

  const unsigned short* Kbase = K  + (size_t)b * Sz * Hz + nh * HDz;
  const unsigned short* Vbase = Vt + (size_t)bh * HDz * Sz;

  f32x4 acc[2][8];
#pragma unroll
  for (int mt = 0; mt < 2; mt++)
#pragma unroll
    for (int i = 0; i < 8; i++) acc[mt][i] = (f32x4){0.f, 0.f, 0.f, 0.f};
  float mrow[2][4], lrow[2][4];
#pragma unroll
  for (int mt = 0; mt < 2; mt++)
#pragma unroll
    for (int r = 0; r < 4; r++) { mrow[mt][r] = -1e30f; lrow[mt][r] = 0.f; }

  // staging: K tile [64 s][128 d], 16 chunks of 16B per row, chunk ^= (row&7)
  //          V tile [128 hd][64 s], 8 chunks of 16B per row, chunk ^= (row&7)
  // linear LDS dest + pre-swizzled global source (involution)
  #define STAGE_K(BUF, KT) {                                                          \
    _Pragma("unroll")                                                                 \
    for (int i = 0; i < 4; i++) {                                                     \
      const int r = w * 16 + i * 4 + (l >> 4);                                        \
      gl2lds16(Kbase + (size_t)((KT) * 64 + r) * Hz + (((l & 15) ^ (r & 7)) * 8),     \
               &Ksm[BUF][(w * 16 + i * 4) * 128]);                                    \
    } }
  #define STAGE_V(KT) {                                                               \
    _Pragma("unroll")                                                                 \
    for (int i = 0; i < 4; i++) {                                                     \
      const int r = w * 32 + i * 8 + (l >> 3);                                        \
      gl2lds16(Vbase + (size_t)r * Sz + (KT) * 64 + (((l & 7) ^ (r & 7)) * 8),        \
               &Vsm[(w * 32 + i * 8) * 64]);                                          \
    } }

  int cur = 0;
  STAGE_K(0, 0);
  __syncthreads();   // K[0] resident

  for (int kt = 0; kt < Sz / 64; kt++) {
    // ---- issue async stages: V for THIS tile, K for NEXT tile
    STAGE_V(kt);
    if (kt < Sz / 64 - 1) STAGE_K(cur ^ 1, kt + 1);

    // ---- QK^T from Ksm[cur] (swizzled reads)
    f32x4 s[2][4];
#pragma unroll
    for (int mt = 0; mt < 2; mt++)
#pragma unroll
      for (int nt = 0; nt < 4; nt++) s[mt][nt] = (f32x4){0.f, 0.f, 0.f, 0.f};
#pragma unroll
    for (int ks = 0; ks < 4; ks++) {
#pragma unroll
      for (int nt = 0; nt < 4; nt++) {
        bf16x8 kf = *(const bf16x8*)&Ksm[cur][(nt * 16 + lc) * 128 + (((ks * 4 + lg) ^ (lc & 7)) * 8)];
#pragma unroll
        for (int mt = 0; mt < 2; mt++)
          s[mt][nt] = __builtin_amdgcn_mfma_f32_16x16x32_bf16(qf[mt][ks], kf, s[mt][nt], 0, 0, 0);
      }
    }

    // ---- online softmax (exp2-space, defer-max THR=8)
#pragma unroll
    for (int mt = 0; mt < 2; mt++) {
#pragma unroll
      for (int r = 0; r < 4; r++) {
        float tm = fmaxf(fmaxf(s[mt][0][r], s[mt][1][r]), fmaxf(s[mt][2][r], s[mt][3][r]));
        tm = fmaxf(tm, __shfl_xor(tm, 1));
        tm = fmaxf(tm, __shfl_xor(tm, 2));
        tm = fmaxf(tm, __shfl_xor(tm, 4));
        tm = fmaxf(tm, __shfl_xor(tm, 8));
        if (tm > mrow[mt][r] + 8.0f) {
          const float sc = exp2f(mrow[mt][r] - tm);
          mrow[mt][r] = tm;
          lrow[mt][r] *= sc;
#pragma unroll
          for (int nt = 0; nt < 8; nt++) acc[mt][nt][r] *= sc;
        }
        float rs = 0.f;
#pragma unroll
        for (int nt = 0; nt < 4; nt++) {
          float p = exp2f(s[mt][nt][r] - mrow[mt][r]);
          s[mt][nt][r] = p;
          rs += p;
        }
        rs += __shfl_xor(rs, 1);
        rs += __shfl_xor(rs, 2);
        rs += __shfl_xor(rs, 4);
        rs += __shfl_xor(rs, 8);
        lrow[mt][r] += rs;
      }
    }

    // ---- P -> LDS (swizzled) -> A-fragments; per-wave buffer reused across m
    bf16x8 pf[2][2];
#pragma unroll
    for (int mt = 0; mt < 2; mt++) {
#pragma unroll
      for (int nt = 0; nt < 4; nt++)
#pragma unroll
        for (int r = 0; r < 4; r++) {
          const int row = lg * 4 + r;
          const int ch  = (nt * 2 + (lc >> 3)) ^ (row & 7);
          Psm[w][row * 64 + ch * 8 + (lc & 7)] = f2bf(s[mt][nt][r]);
        }
#pragma unroll
      for (int kk = 0; kk < 2; kk++)
        pf[mt][kk] = *(const bf16x8*)&Psm[w][lc * 64 + (((kk * 4 + lg) ^ (lc & 7)) * 8)];
    }

    __syncthreads();   // V[kt] (and K[kt+1]) resident; all waves past QK^T reads

    // ---- PV from Vsm (swizzled reads), vf shared across m
#pragma unroll
    for (int kk = 0; kk < 2; kk++) {
#pragma unroll
      for (int nt = 0; nt < 8; nt++) {
        bf16x8 vf = *(const bf16x8*)&Vsm[(nt * 16 + lc) * 64 + (((kk * 4 + lg) ^ (lc & 7)) * 8)];
        acc[0][nt] = __builtin_amdgcn_mfma_f32_16x16x32_bf16(pf[0][kk], vf, acc[0][nt], 0, 0, 0);
        acc[1][nt] = __builtin_amdgcn_mfma_f32_16x16x32_bf16(pf[1][kk], vf, acc[1][nt], 0, 0, 0);
      }
    }

    __syncthreads();   // Vsm / Ksm[cur] safe to overwrite next iter
    cur ^= 1;
  }

  // ---- epilogue
#pragma unroll
  for (int mt = 0; mt < 2; mt++)
#pragma unroll
    for (int nt = 0; nt < 8; nt++)
#pragma unroll
      for (int r = 0; r < 4; r++) {
        const size_t row = (size_t)b * Sz + qb * 128 + w * 32 + mt * 16 + lg * 4 + r;
        O[row * Hz + nh * HDz + nt * 16 + lc] = f2bf(acc[mt][nt][r] / lrow[mt][r]);
      }
}

// ---------------------------------------------------------------- launch
extern "C" void kernel_launch(void* const* d_in, const int* in_sizes, int n_in,
                              void* d_out, int out_size, void* d_ws, size_t ws_size,
                              hipStream_t stream) {
  const float* hs = (const float*)d_in[0];
  const float* Wq = (const float*)d_in[1];
  const float* Wk = (const float*)d_in[2];
  const float* Wv = (const float*)d_in[3];
  const float* Wo = (const float*)d_in[4];

  const size_t NEL = (size_t)Mz * Hz;   // 8388608
  const size_t WEL = (size_t)Hz * Hz;   // 1048576

  unsigned short* p = (unsigned short*)d_ws;
  unsigned short* hs_bf = p; p += NEL;
  unsigned short* Wq_bf = p; p += WEL;
  unsigned short* Wk_bf = p; p += WEL;
  unsigned short* Wv_bf = p; p += WEL;
  unsigned short* Wo_bf = p; p += WEL;
  unsigned short* Qb    = p; p += NEL;
  unsigned short* Kb    = p; p += NEL;
  unsigned short* Vtb   = p; p += NEL;
  unsigned short* Ob    = hs_bf;        // alias: hs_bf dead after V GEMM

  cvt_kernel<<<2048, 256, 0, stream>>>(hs, hs_bf, (int)NEL);
  cvt4_kernel<<<dim3(512, 4), 256, 0, stream>>>(Wq, Wk, Wv, Wo,
                                                Wq_bf, Wk_bf, Wv_bf, Wo_bf);

  dim3 gg(Mz / 128, Hz / 128);  // 64 x 8
  const float qscale = 0.08838834764831845f * 1.44269504088896340736f; // 1/sqrt(128)*log2(e)
  gemm_bt_k<true,  false><<<gg, 256, 0, stream>>>(hs_bf, Wq_bf, Qb,  qscale);
  gemm_bt_k<true,  false><<<gg, 256, 0, stream>>>(hs_bf, Wk_bf, Kb,  1.0f);
  gemm_bt_k<true,  true ><<<gg, 256, 0, stream>>>(hs_bf, Wv_bf, Vtb, 1.0f);

  attn_fwd<<<512, 256, 0, stream>>>(Qb, Kb, Vtb, Ob);

  gemm_bt_k<false, false><<<gg, 256, 0, stream>>>(Ob, Wo_bf, (float*)d_out, 1.0f);
}